// Round 3
// baseline (305.786 us; speedup 1.0000x reference)
//
#include <hip/hip_runtime.h>
#include <cstddef>
#include <cstdint>

#define EMBED 1024
#define NH    16
#define DQ    64
#define NB    4
#define LSEQ  2048
#define MROWS (NB * LSEQ)   // 8192

typedef __bf16 bf16x8 __attribute__((ext_vector_type(8)));
typedef __bf16 bf16x4 __attribute__((ext_vector_type(4)));
typedef float  f32x4  __attribute__((ext_vector_type(4)));

// bf16 round-half-up: bias then take high 16. (RNE differs only on exact ties.)
__device__ __forceinline__ unsigned short f2bf(float f) {
    return (unsigned short)((__float_as_uint(f) + 0x8000u) >> 16);
}

// two floats -> packed bf16x2, round-half-up: 2 bias adds + 1 v_perm_b32.
__device__ __forceinline__ unsigned pack2(float a, float b) {
    unsigned ua = __float_as_uint(a) + 0x8000u;
    unsigned ub = __float_as_uint(b) + 0x8000u;
    return __builtin_amdgcn_perm(ub, ua, 0x07060302u);  // [b.hi16 : a.hi16]
}

__device__ __forceinline__ uint2 pack4(float a, float b, float c, float d) {
    return make_uint2(pack2(a, b), pack2(c, d));
}

// truncating pack (1 v_perm, no bias). Used for P where the bias cancels in
// the O = (P@V)/(P@1) ratio since l is computed from the same truncated P.
__device__ __forceinline__ unsigned pack2t(float a, float b) {
    return __builtin_amdgcn_perm(__float_as_uint(b), __float_as_uint(a), 0x07060302u);
}

// async global -> LDS, 16 B per lane. LDS dest = l + lane*16 (wave-uniform base l).
__device__ __forceinline__ void async_cp16(const void* g, void* l) {
    __builtin_amdgcn_global_load_lds((const __attribute__((address_space(1))) unsigned int*)g,
                                     (__attribute__((address_space(3))) unsigned int*)l,
                                     16, 0, 0);
}

// ---------------- fp32 -> bf16 convert (batched) ----------------
struct CvtJobs {
    const float* src[8];
    unsigned short* dst[8];
    int n[8];
};

__global__ __launch_bounds__(256) void cvt_bf16(CvtJobs j) {
    int job = blockIdx.y;
    const float* s = j.src[job];
    unsigned short* d = j.dst[job];
    int n4 = j.n[job] >> 2;
    int stride = gridDim.x * blockDim.x;
    for (int i = blockIdx.x * blockDim.x + threadIdx.x; i < n4; i += stride) {
        float4 f = ((const float4*)s)[i];
        ((uint2*)d)[i] = pack4(f.x, f.y, f.z, f.w);
    }
}

// ---------------- fp32 -> bf16 transposed convert (1024x1024) ----------------
// dst[j][i] = bf16(src[i][j]). 64x64 tiles, grid (16,16,3).
struct TransJobs {
    const float* src[3];
    unsigned short* dst[3];
};

__global__ __launch_bounds__(256) void transpose_cvt(TransJobs tj) {
    __shared__ unsigned short Ts[64][68];
    const float* src = tj.src[blockIdx.z];
    unsigned short* dst = tj.dst[blockIdx.z];
    const int tid = threadIdx.x;
    const int r0 = blockIdx.y * 64;
    const int c0 = blockIdx.x * 64;

    {
        int col4 = tid & 15;
        int rb   = tid >> 4;
#pragma unroll
        for (int it = 0; it < 4; it++) {
            int r = rb + it * 16;
            float4 f = *(const float4*)(src + (size_t)(r0 + r) * 1024 + c0 + col4 * 4);
            *(uint2*)&Ts[r][col4 * 4] = pack4(f.x, f.y, f.z, f.w);
        }
    }
    __syncthreads();

    {
        int oc = tid >> 2;
        int seg = tid & 3;
        __attribute__((aligned(16))) unsigned short tmp[16];
#pragma unroll
        for (int e = 0; e < 16; e++) tmp[e] = Ts[seg * 16 + e][oc];
        unsigned short* out = dst + (size_t)(c0 + oc) * 1024 + r0 + seg * 16;
        *(uint4*)(out)     = *(const uint4*)&tmp[0];
        *(uint4*)(out + 8) = *(const uint4*)&tmp[8];
    }
}

// ---------------- bf16 NT GEMM: C = A(MxK) @ B(NxK)^T ----------------
// 128x128 tile, BK=64 (32 KB LDS, 32 MFMA per barrier pair), 256 threads =
// 4 waves, each wave a 64x64 quadrant of 4x4 mfma_f32_16x16x32_bf16.
// Staging via global_load_lds w=16 with xor chunk swizzle:
//   LDS chunk c (16B) holds global (row r=c>>3, k-chunk (c&7)^(r&7)).
// XCD-chunked block swizzle (per-z nwg is a multiple of 8 in all our
// launches -> bijective): the 8 blocks sharing one A row-panel land on ONE
// XCD's L2 instead of 8, cutting A re-fetch ~8x.
// mode: 0 = bf16 row-major (acc*scl), 1 = fp32 row-major, 2 = bf16 C^T (ld=M)
// mode 2 transposes through LDS (reusing As/Bs) so global writes are
// 256B-contiguous runs instead of 8B-at-16KB-stride scatter.
struct BGemmArgs {
    const unsigned short* A[3];
    const unsigned short* B[3];
    void* C[3];
    int mode[3];
    float scl[3];
};

__global__ __launch_bounds__(256) void gemm_bf16nt(BGemmArgs p, int M, int N, int K) {
    __shared__ __align__(16) unsigned short SMEM[2 * 128 * 64];
    unsigned short* As = SMEM;
    unsigned short* Bs = SMEM + 128 * 64;

    const int tid  = threadIdx.x;
    const int wave = tid >> 6;
    const int lane = tid & 63;
    const int m16  = lane & 15;
    const int kq   = lane >> 4;

    // XCD swizzle within the z-slice (nwg % 8 == 0 for all our grids).
    const int nwg  = gridDim.x * gridDim.y;
    const int flat = blockIdx.y * gridDim.x + blockIdx.x;
    const int swz  = (flat & 7) * (nwg >> 3) + (flat >> 3);
    const int bm = (swz / gridDim.x) * 128;
    const int bn = (swz % gridDim.x) * 128;
    const int z  = blockIdx.z;
    const unsigned short* A = p.A[z];
    const unsigned short* B = p.B[z];

    f32x4 acc[4][4];
#pragma unroll
    for (int i = 0; i < 4; i++)
#pragma unroll
        for (int j = 0; j < 4; j++) acc[i][j] = f32x4{0.f, 0.f, 0.f, 0.f};

    const int wr = (wave >> 1) * 64;
    const int wc = (wave & 1) * 64;

    for (int k0 = 0; k0 < K; k0 += 64) {
#pragma unroll
        for (int it = 0; it < 4; it++) {
            int c = tid + it * 256;         // chunk 0..1023
            int r = c >> 3;                 // tile row 0..127
            int kc = (c & 7) ^ (r & 7);     // swizzled k-chunk in row
            async_cp16(A + (size_t)(bm + r) * K + k0 + kc * 8,
                       &As[(it * 256 + wave * 64) * 8]);
            async_cp16(B + (size_t)(bn + r) * K + k0 + kc * 8,
                       &Bs[(it * 256 + wave * 64) * 8]);
        }
        __syncthreads();

#pragma unroll
        for (int s = 0; s < 2; s++) {
            bf16x8 af[4], bfr[4];
#pragma unroll
            for (int i = 0; i < 4; i++) {
                int ra = wr + i * 16 + m16;
                af[i] = *reinterpret_cast<const bf16x8*>(
                    &As[ra * 64 + (((s * 4 + kq) ^ (ra & 7)) * 8)]);
                int rb = wc + i * 16 + m16;
                bfr[i] = *reinterpret_cast<const bf16x8*>(
                    &Bs[rb * 64 + (((s * 4 + kq) ^ (rb & 7)) * 8)]);
            }
#pragma unroll
            for (int i = 0; i < 4; i++)
#pragma unroll
                for (int j = 0; j < 4; j++)
                    acc[i][j] = __builtin_amdgcn_mfma_f32_16x16x32_bf16(af[i], bfr[j], acc[i][j], 0, 0, 0);
        }
        __syncthreads();
    }

    const int mode = p.mode[z];
    const float scl = p.scl[z];
    if (mode == 0) {
        unsigned short* Cb = (unsigned short*)p.C[z];
#pragma unroll
        for (int i = 0; i < 4; i++)
#pragma unroll
            for (int j = 0; j < 4; j++) {
                int row = bm + wr + i * 16 + kq * 4;
                int col = bn + wc + j * 16 + m16;
#pragma unroll
                for (int q = 0; q < 4; q++)
                    Cb[(size_t)(row + q) * N + col] = f2bf(acc[i][j][q] * scl);
            }
    } else if (mode == 1) {
        float* Cf = (float*)p.C[z];
#pragma unroll
        for (int i = 0; i < 4; i++)
#pragma unroll
            for (int j = 0; j < 4; j++) {
                int row = bm + wr + i * 16 + kq * 4;
                int col = bn + wc + j * 16 + m16;
#pragma unroll
                for (int q = 0; q < 4; q++)
                    Cf[(size_t)(row + q) * N + col] = acc[i][j][q];
            }
    } else {
        // C^T through LDS. Last loop iteration ended with __syncthreads(),
        // so As/Bs are free to reuse as the 128x128 bf16 transpose buffer.
        // Layout: Tt[col][row-unit], row-unit = 4 rows (8 B). Add-rotate
        // swizzle u' = (u + 2*col) & 31 spreads banks (<=2-way conflicts)
        // with zero padding, so the buffer is exactly 32 KB.
        unsigned short* Tt = SMEM;
#pragma unroll
        for (int i = 0; i < 4; i++)
#pragma unroll
            for (int j = 0; j < 4; j++) {
                int c = wc + j * 16 + m16;          // local col 0..127 (N-dim)
                int u = (wr >> 2) + i * 4 + kq;     // row unit 0..31 (M-dim/4)
                int us = (u + 2 * c) & 31;
                *reinterpret_cast<uint2*>(&Tt[c * 128 + us * 4]) =
                    pack4(acc[i][j][0], acc[i][j][1], acc[i][j][2], acc[i][j][3]);
            }
        __syncthreads();
        unsigned short* Ct = (unsigned short*)p.C[z];
        int r8 = tid & 15;          // 8-row chunk within tile
        int cb = tid >> 4;          // col offset within pass
#pragma unroll
        for (int pass = 0; pass < 8; pass++) {
            int c  = pass * 16 + cb;
            int u0 = r8 * 2;                       // even -> us,us+1 contiguous
            int us = (u0 + 2 * c) & 31;
            uint4 val = *reinterpret_cast<const uint4*>(&Tt[c * 128 + us * 4]);
            *reinterpret_cast<uint4*>(&Ct[(size_t)(bn + c) * M + bm + r8 * 8]) = val;
        }
    }
}

// ---------------- flash attention, bf16 MFMA, no-max softmax ----------------
// Q is pre-scaled by 0.125*log2(e) in the projection GEMM epilogue, so
//   p = exp2(k.q_scaled) == exp(q.k/8)  (|q.k/8| <~ 2 -> no-max is safe).
// Row-sum l is folded into the PV stage: extra MFMAs with an all-ones
// A-fragment compute column sums of P^T; in the C/D layout every lane then
// holds l for its own q-column in all regs -> no adds, no shuffles.
// P is packed to bf16 by TRUNCATION; bias cancels in O = (P@V)/(P@1).
// Orientation: St = K @ Q^T (m=key, n=qrow), O^T = V^T @ P^T (m=d, n=qrow).
// Block: 128 q-rows, 4 waves, wave owns 32 q-rows. Key-tile 64. Grid 1024.
//
// v4: (a) zero-shuffle PV: the QK C/D layout (key=kq*4+reg, qcol=m16) IS the
//     B-operand layout of v_mfma_f32_16x16x16_bf16 (k=(lane>>4)*4+e, n=m16),
//     so P feeds PV straight from registers. Pt LDS buffer + 12 LDS ops +
//     its bank conflicts are deleted. V^T is read as ds_read_b64 fragments.
//     (b) with Pt gone, K/V double-buffer fits in 32 KB (5 blocks/CU cap,
//     grid gives 4): T3 2-phase — stage(next) at iter top, one
//     vmcnt(0)+s_barrier at iter end; staging latency hides under compute.
//     (c) T5 setprio around MFMA clusters.
//     XCD-chunked block swizzle kept (FETCH 141.6 -> 26.6 MB).
__global__ __launch_bounds__(256, 4)
void flash_bf16(const unsigned short* __restrict__ qb,
                const unsigned short* __restrict__ kb,
                const unsigned short* __restrict__ vtb,
                unsigned short* __restrict__ ao) {
    __shared__ __align__(16) unsigned short Ks[2][64 * 64];
    __shared__ __align__(16) unsigned short Vt[2][64 * 64];

    const int tid  = threadIdx.x;
    const int wave = tid >> 6;
    const int lane = tid & 63;
    const int m16  = lane & 15;
    const int kq   = lane >> 4;

    // XCD swizzle: linear dispatch id -> 128-contiguous chunk per XCD.
    const int flat = blockIdx.y * (LSEQ / 128) + blockIdx.x;   // 0..1023
    const int swz  = (flat & 7) * 128 + (flat >> 3);
    const int bh   = swz >> 4;               // 0..63
    const int nn   = bh >> 4;                // batch
    const int h    = bh & 15;                // head
    const int q0   = (swz & 15) * 128;       // query tile base

    // all-ones A-fragment (bf16 1.0 = 0x3F80) for the l-row MFMAs
    const uint2 ones_u = make_uint2(0x3F803F80u, 0x3F803F80u);
    const bf16x4 ones4 = __builtin_bit_cast(bf16x4, ones_u);

    const unsigned short* kptr  = kb + (size_t)(nn * LSEQ) * EMBED + h * DQ;
    const unsigned short* vtptr = vtb + (size_t)(h * DQ) * MROWS + nn * LSEQ;

    auto stage = [&](int buf) {
#pragma unroll
        for (int it = 0; it < 2; it++) {
            int c = tid + it * 256;            // chunk 0..511
            int r = c >> 3;                    // row 0..63
            int kc = (c & 7) ^ (r & 7);        // swizzled chunk in row
            async_cp16(kptr + (size_t)r * EMBED + kc * 8,
                       &Ks[buf][(it * 256 + wave * 64) * 8]);
            async_cp16(vtptr + (size_t)r * MROWS + kc * 8,
                       &Vt[buf][(it * 256 + wave * 64) * 8]);
        }
        kptr  += 64 * EMBED;
        vtptr += 64;
    };

    // prologue: stage tile 0; Q fragment loads overlap the staging.
    stage(0);

    // Q fragments: qf[j][s] = Q[q0+wave*32+j*16+m16][s*32 + kq*8 .. +7]
    bf16x8 qf[2][2];
#pragma unroll
    for (int j = 0; j < 2; j++) {
        size_t tok = (size_t)(nn * LSEQ + q0 + wave * 32 + j * 16 + m16);
#pragma unroll
        for (int s = 0; s < 2; s++)
            qf[j][s] = *reinterpret_cast<const bf16x8*>(
                &qb[tok * EMBED + h * DQ + s * 32 + kq * 8]);
    }

    f32x4 o[4][2];   // o[mt][j]: O^T tile (d = mt*16+kq*4+reg, qcol = j*16+m16)
    f32x4 o4[2];     // l accumulator (all regs equal per lane)
#pragma unroll
    for (int j = 0; j < 2; j++) {
        o4[j] = f32x4{0.f, 0.f, 0.f, 0.f};
#pragma unroll
        for (int mt = 0; mt < 4; mt++) o[mt][j] = f32x4{0.f, 0.f, 0.f, 0.f};
    }

    asm volatile("s_waitcnt vmcnt(0)" ::: "memory");   // tile 0 + Q landed
    __builtin_amdgcn_s_barrier();
    asm volatile("" ::: "memory");

    const int NT = LSEQ / 64;    // 32
    for (int kt = 0; kt < NT; kt++) {
        const int cur = kt & 1;
        if (kt + 1 < NT) stage(cur ^ 1);   // prefetch next tile (no wait)

        // St = K @ Q^T : st[i][j], key = i*16+kq*4+reg, qcol = j*16+m16
        f32x4 st[4][2];
#pragma unroll
        for (int i = 0; i < 4; i++)
#pragma unroll
            for (int j = 0; j < 2; j++) st[i][j] = f32x4{0.f, 0.f, 0.f, 0.f};

#pragma unroll
        for (int s = 0; s < 2; s++) {
            bf16x8 ak[4];
#pragma unroll
            for (int i = 0; i < 4; i++) {
                int key = i * 16 + m16;
                ak[i] = *reinterpret_cast<const bf16x8*>(
                    &Ks[cur][key * 64 + (((s * 4 + kq) ^ (m16 & 7)) * 8)]);
            }
            __builtin_amdgcn_s_setprio(1);
#pragma unroll
            for (int i = 0; i < 4; i++)
#pragma unroll
                for (int j = 0; j < 2; j++)
                    st[i][j] = __builtin_amdgcn_mfma_f32_16x16x32_bf16(ak[i], qf[j][s], st[i][j], 0, 0, 0);
            __builtin_amdgcn_s_setprio(0);
        }

        // p = exp2(st) (Q pre-scaled), then pack to bf16x4 B-fragments.
        // pb[i][j] elems [0..3] = C/D regs [0..3] = keys kq*4+{0..3}+16i.
        bf16x4 pb[4][2];
#pragma unroll
        for (int i = 0; i < 4; i++)
#pragma unroll
            for (int j = 0; j < 2; j++) {
#pragma unroll
                for (int q = 0; q < 4; q++)
                    st[i][j][q] = __builtin_amdgcn_exp2f(st[i][j][q]);
                uint2 u = make_uint2(pack2t(st[i][j][0], st[i][j][1]),
                                     pack2t(st[i][j][2], st[i][j][3]));
                pb[i][j] = __builtin_bit_cast(bf16x4, u);
            }

        // O^T += V^T @ P^T and l += 1^T @ P^T, four 16-key blocks, K=16 MFMA.
        // A-frag: av4[mt] = V^T[d = mt*16+m16][key = i*16 + kq*4 + 0..3].
#pragma unroll
        for (int i = 0; i < 4; i++) {
            bf16x4 av4[4];
#pragma unroll
            for (int mt = 0; mt < 4; mt++) {
                int d = mt * 16 + m16;
                av4[mt] = *reinterpret_cast<const bf16x4*>(
                    &Vt[cur][d * 64 + (((2 * i + (kq >> 1)) ^ (d & 7)) * 8) + (kq & 1) * 4]);
            }
            __builtin_amdgcn_s_setprio(1);
#pragma unroll
            for (int mt = 0; mt < 4; mt++)
#pragma unroll
                for (int j = 0; j < 2; j++)
                    o[mt][j] = __builtin_amdgcn_mfma_f32_16x16x16bf16_1k(av4[mt], pb[i][j], o[mt][j], 0, 0, 0);
#pragma unroll
            for (int j = 0; j < 2; j++)
                o4[j] = __builtin_amdgcn_mfma_f32_16x16x16bf16_1k(ones4, pb[i][j], o4[j], 0, 0, 0);
            __builtin_amdgcn_s_setprio(0);
        }

        // Release buf[cur] for next iter's stage; next tile's loads (issued
        // at iter top) drained here, hidden under the compute above.
        if (kt + 1 < NT) {
            asm volatile("s_waitcnt vmcnt(0)" ::: "memory");
            __builtin_amdgcn_s_barrier();
            asm volatile("" ::: "memory");
        }
    }

    // Epilogue: normalize by l (= o4[j][0], identical in all regs), write ao.
#pragma unroll
    for (int j = 0; j < 2; j++) {
        float inv = 1.f / o4[j][0];
        size_t tok = (size_t)(nn * LSEQ + q0 + wave * 32 + j * 16 + m16);
#pragma unroll
        for (int mt = 0; mt < 4; mt++) {
            *reinterpret_cast<uint2*>(&ao[tok * EMBED + h * DQ + mt * 16 + kq * 4]) =
                pack4(o[mt][j][0] * inv, o[mt][j][1] * inv, o[mt][j][2] * inv, o[mt][j][3] * inv);
        }
    }
}

// ---------------- host ----------------
extern "C" void kernel_launch(void* const* d_in, const int* in_sizes, int n_in,
                              void* d_out, int out_size, void* d_ws, size_t ws_size,
                              hipStream_t stream) {
    (void)in_sizes; (void)n_in; (void)out_size; (void)ws_size;
    const float* x     = (const float*)d_in[0];
    const float* W_q   = (const float*)d_in[1];
    const float* W_k   = (const float*)d_in[2];
    const float* W_v   = (const float*)d_in[3];
    const float* W_qp  = (const float*)d_in[4];
    const float* W_kp  = (const float*)d_in[5];
    const float* W_vp  = (const float*)d_in[6];
    const float* W_out = (const float*)d_in[7];

    unsigned short* ws16 = (unsigned short*)d_ws;
    const size_t SZX = (size_t)MROWS * EMBED;   // 8,388,608
    const size_t SZW = (size_t)EMBED * EMBED;   // 1,048,576

    unsigned short* xb    = ws16;
    unsigned short* wqpb  = xb + SZX;
    unsigned short* wkpb  = wqpb + SZW;
    unsigned short* wvpb  = wkpb + SZW;
    unsigned short* woutb = wvpb + SZW;
    unsigned short* wqT   = woutb + SZW;        // transposed bf16 first-layer weights
    unsigned short* wkT   = wqT + SZW;
    unsigned short* wvT   = wkT + SZW;
    unsigned short* weq   = wvT + SZW;          // fused W_eff = W_p @ W
    unsigned short* wek   = weq + SZW;
    unsigned short* wev   = wek + SZW;
    unsigned short* qbuf  = wev + SZW;
    unsigned short* kbuf  = qbuf + SZX;
    unsigned short* vtbuf = kbuf + SZX;
    unsigned short* ao    = vtbuf + SZX;
    // total: 5*SZX + 10*SZW shorts ~= 105 MB

    // 1a) straight converts: x, Wqp, Wkp, Wvp, Wout
    CvtJobs cj;
    cj.src[0] = x;     cj.dst[0] = xb;    cj.n[0] = (int)SZX;
    cj.src[1] = W_qp;  cj.dst[1] = wqpb;  cj.n[1] = (int)SZW;
    cj.src[2] = W_kp;  cj.dst[2] = wkpb;  cj.n[2] = (int)SZW;
    cj.src[3] = W_vp;  cj.dst[3] = wvpb;  cj.n[3] = (int)SZW;
    cj.src[4] = W_out; cj.dst[4] = woutb; cj.n[4] = (int)SZW;
    cvt_bf16<<<dim3(512, 5), 256, 0, stream>>>(cj);

    // 1b) transposed converts: Wq^T, Wk^T, Wv^T
    TransJobs tj;
    tj.src[0] = W_q; tj.src[1] = W_k; tj.src[2] = W_v;
    tj.dst[0] = wqT; tj.dst[1] = wkT; tj.dst[2] = wvT;
    transpose_cvt<<<dim3(16, 16, 3), 256, 0, stream>>>(tj);

    // 2) weight fusion: W_eff = W_p @ W  (NT with B = W^T)
    BGemmArgs fz;
    fz.A[0] = wqpb; fz.A[1] = wkpb; fz.A[2] = wvpb;
    fz.B[0] = wqT;  fz.B[1] = wkT;  fz.B[2] = wvT;
    fz.C[0] = weq;  fz.C[1] = wek;  fz.C[2] = wev;
    fz.mode[0] = 0; fz.mode[1] = 0; fz.mode[2] = 0;
    fz.scl[0] = 1.f; fz.scl[1] = 1.f; fz.scl[2] = 1.f;
    gemm_bf16nt<<<dim3(8, 8, 3), 256, 0, stream>>>(fz, EMBED, EMBED, EMBED);

    // 3) projections: q = (x@Weq^T)*0.125*log2e, k = x@Wek^T, v^T = (x@Wev^T)^T
    BGemmArgs pj;
    pj.A[0] = xb;   pj.A[1] = xb;   pj.A[2] = xb;
    pj.B[0] = weq;  pj.B[1] = wek;  pj.B[2] = wev;
    pj.C[0] = qbuf; pj.C[1] = kbuf; pj.C[2] = vtbuf;
    pj.mode[0] = 0; pj.mode[1] = 0; pj.mode[2] = 2;
    pj.scl[0] = 0.18033688f; pj.scl[1] = 1.f; pj.scl[2] = 1.f;
    gemm_bf16nt<<<dim3(8, 64, 3), 256, 0, stream>>>(pj, MROWS, EMBED, EMBED);

    // 4) flash attention
    flash_bf16<<<dim3(LSEQ / 128, NB * NH), 256, 0, stream>>>(qbuf, kbuf, vtbuf, ao);

    // 5) out = ao @ W_out^T (fp32 out)
    BGemmArgs og;
    og.A[0] = ao;    og.A[1] = ao;    og.A[2] = ao;
    og.B[0] = woutb; og.B[1] = woutb; og.B[2] = woutb;
    og.C[0] = d_out; og.C[1] = d_out; og.C[2] = d_out;
    og.mode[0] = 1; og.mode[1] = 1; og.mode[2] = 1;
    og.scl[0] = 1.f; og.scl[1] = 1.f; og.scl[2] = 1.f;
    gemm_bf16nt<<<dim3(8, 64, 1), 256, 0, stream>>>(og, MROWS, EMBED, EMBED);
}

// Round 4
// 297.653 us; speedup vs baseline: 1.0273x; 1.0273x over previous
//
#include <hip/hip_runtime.h>
#include <cstddef>
#include <cstdint>

#define EMBED 1024
#define NH    16
#define DQ    64
#define NB    4
#define LSEQ  2048
#define MROWS (NB * LSEQ)   // 8192

typedef __bf16 bf16x8 __attribute__((ext_vector_type(8)));
typedef float  f32x4  __attribute__((ext_vector_type(4)));

// bf16 round-half-up: bias then take high 16. (RNE differs only on exact ties.)
__device__ __forceinline__ unsigned short f2bf(float f) {
    return (unsigned short)((__float_as_uint(f) + 0x8000u) >> 16);
}

// two floats -> packed bf16x2, round-half-up: 2 bias adds + 1 v_perm_b32.
__device__ __forceinline__ unsigned pack2(float a, float b) {
    unsigned ua = __float_as_uint(a) + 0x8000u;
    unsigned ub = __float_as_uint(b) + 0x8000u;
    return __builtin_amdgcn_perm(ub, ua, 0x07060302u);  // [b.hi16 : a.hi16]
}

__device__ __forceinline__ uint2 pack4(float a, float b, float c, float d) {
    return make_uint2(pack2(a, b), pack2(c, d));
}

// truncating pack (1 v_perm, no bias). Used for P where the bias cancels in
// the O = (P@V)/(P@1) ratio since l is computed from the same truncated P.
__device__ __forceinline__ unsigned pack2t(float a, float b) {
    return __builtin_amdgcn_perm(__float_as_uint(b), __float_as_uint(a), 0x07060302u);
}

// async global -> LDS, 16 B per lane. LDS dest = l + lane*16 (wave-uniform base l).
__device__ __forceinline__ void async_cp16(const void* g, void* l) {
    __builtin_amdgcn_global_load_lds((const __attribute__((address_space(1))) unsigned int*)g,
                                     (__attribute__((address_space(3))) unsigned int*)l,
                                     16, 0, 0);
}

// ---------------- fp32 -> bf16 convert (batched) ----------------
struct CvtJobs {
    const float* src[8];
    unsigned short* dst[8];
    int n[8];
};

__global__ __launch_bounds__(256) void cvt_bf16(CvtJobs j) {
    int job = blockIdx.y;
    const float* s = j.src[job];
    unsigned short* d = j.dst[job];
    int n4 = j.n[job] >> 2;
    int stride = gridDim.x * blockDim.x;
    for (int i = blockIdx.x * blockDim.x + threadIdx.x; i < n4; i += stride) {
        float4 f = ((const float4*)s)[i];
        ((uint2*)d)[i] = pack4(f.x, f.y, f.z, f.w);
    }
}

// ---------------- fp32 -> bf16 transposed convert (1024x1024) ----------------
// dst[j][i] = bf16(src[i][j]). 64x64 tiles, grid (16,16,3).
struct TransJobs {
    const float* src[3];
    unsigned short* dst[3];
};

__global__ __launch_bounds__(256) void transpose_cvt(TransJobs tj) {
    __shared__ unsigned short Ts[64][68];
    const float* src = tj.src[blockIdx.z];
    unsigned short* dst = tj.dst[blockIdx.z];
    const int tid = threadIdx.x;
    const int r0 = blockIdx.y * 64;
    const int c0 = blockIdx.x * 64;

    {
        int col4 = tid & 15;
        int rb   = tid >> 4;
#pragma unroll
        for (int it = 0; it < 4; it++) {
            int r = rb + it * 16;
            float4 f = *(const float4*)(src + (size_t)(r0 + r) * 1024 + c0 + col4 * 4);
            *(uint2*)&Ts[r][col4 * 4] = pack4(f.x, f.y, f.z, f.w);
        }
    }
    __syncthreads();

    {
        int oc = tid >> 2;
        int seg = tid & 3;
        __attribute__((aligned(16))) unsigned short tmp[16];
#pragma unroll
        for (int e = 0; e < 16; e++) tmp[e] = Ts[seg * 16 + e][oc];
        unsigned short* out = dst + (size_t)(c0 + oc) * 1024 + r0 + seg * 16;
        *(uint4*)(out)     = *(const uint4*)&tmp[0];
        *(uint4*)(out + 8) = *(const uint4*)&tmp[8];
    }
}

// ---------------- bf16 NT GEMM: C = A(MxK) @ B(NxK)^T ----------------
// 128x128 tile, BK=64 (32 KB LDS, 32 MFMA per barrier pair), 256 threads =
// 4 waves, each wave a 64x64 quadrant of 4x4 mfma_f32_16x16x32_bf16.
// Staging via global_load_lds w=16 with xor chunk swizzle:
//   LDS chunk c (16B) holds global (row r=c>>3, k-chunk (c&7)^(r&7)).
// XCD-chunked block swizzle (per-z nwg is a multiple of 8 in all our
// launches -> bijective): the 8 blocks sharing one A row-panel land on ONE
// XCD's L2 instead of 8, cutting A re-fetch ~8x.
// mode: 0 = bf16 row-major (acc*scl), 1 = fp32 row-major,
// mode 2 = bf16 C^T (ld=M) with KEY-PERMUTED rows for the flash PV B-layout:
//   within each 32-row group, row 16h+4g+e  is stored at  8g+4h+e.
//   (PV contracts V^T and P^T over the same permuted index; permutation
//   applied identically to both operands leaves the product unchanged.)
//   Transposes through LDS so global writes stay 8B-unit contiguous runs.
struct BGemmArgs {
    const unsigned short* A[3];
    const unsigned short* B[3];
    void* C[3];
    int mode[3];
    float scl[3];
};

__global__ __launch_bounds__(256) void gemm_bf16nt(BGemmArgs p, int M, int N, int K) {
    __shared__ __align__(16) unsigned short SMEM[2 * 128 * 64];
    unsigned short* As = SMEM;
    unsigned short* Bs = SMEM + 128 * 64;

    const int tid  = threadIdx.x;
    const int wave = tid >> 6;
    const int lane = tid & 63;
    const int m16  = lane & 15;
    const int kq   = lane >> 4;

    // XCD swizzle within the z-slice (nwg % 8 == 0 for all our grids).
    const int nwg  = gridDim.x * gridDim.y;
    const int flat = blockIdx.y * gridDim.x + blockIdx.x;
    const int swz  = (flat & 7) * (nwg >> 3) + (flat >> 3);
    const int bm = (swz / gridDim.x) * 128;
    const int bn = (swz % gridDim.x) * 128;
    const int z  = blockIdx.z;
    const unsigned short* A = p.A[z];
    const unsigned short* B = p.B[z];

    f32x4 acc[4][4];
#pragma unroll
    for (int i = 0; i < 4; i++)
#pragma unroll
        for (int j = 0; j < 4; j++) acc[i][j] = f32x4{0.f, 0.f, 0.f, 0.f};

    const int wr = (wave >> 1) * 64;
    const int wc = (wave & 1) * 64;

    for (int k0 = 0; k0 < K; k0 += 64) {
#pragma unroll
        for (int it = 0; it < 4; it++) {
            int c = tid + it * 256;         // chunk 0..1023
            int r = c >> 3;                 // tile row 0..127
            int kc = (c & 7) ^ (r & 7);     // swizzled k-chunk in row
            async_cp16(A + (size_t)(bm + r) * K + k0 + kc * 8,
                       &As[(it * 256 + wave * 64) * 8]);
            async_cp16(B + (size_t)(bn + r) * K + k0 + kc * 8,
                       &Bs[(it * 256 + wave * 64) * 8]);
        }
        __syncthreads();

#pragma unroll
        for (int s = 0; s < 2; s++) {
            bf16x8 af[4], bfr[4];
#pragma unroll
            for (int i = 0; i < 4; i++) {
                int ra = wr + i * 16 + m16;
                af[i] = *reinterpret_cast<const bf16x8*>(
                    &As[ra * 64 + (((s * 4 + kq) ^ (ra & 7)) * 8)]);
                int rb = wc + i * 16 + m16;
                bfr[i] = *reinterpret_cast<const bf16x8*>(
                    &Bs[rb * 64 + (((s * 4 + kq) ^ (rb & 7)) * 8)]);
            }
#pragma unroll
            for (int i = 0; i < 4; i++)
#pragma unroll
                for (int j = 0; j < 4; j++)
                    acc[i][j] = __builtin_amdgcn_mfma_f32_16x16x32_bf16(af[i], bfr[j], acc[i][j], 0, 0, 0);
        }
        __syncthreads();
    }

    const int mode = p.mode[z];
    const float scl = p.scl[z];
    if (mode == 0) {
        unsigned short* Cb = (unsigned short*)p.C[z];
#pragma unroll
        for (int i = 0; i < 4; i++)
#pragma unroll
            for (int j = 0; j < 4; j++) {
                int row = bm + wr + i * 16 + kq * 4;
                int col = bn + wc + j * 16 + m16;
#pragma unroll
                for (int q = 0; q < 4; q++)
                    Cb[(size_t)(row + q) * N + col] = f2bf(acc[i][j][q] * scl);
            }
    } else if (mode == 1) {
        float* Cf = (float*)p.C[z];
#pragma unroll
        for (int i = 0; i < 4; i++)
#pragma unroll
            for (int j = 0; j < 4; j++) {
                int row = bm + wr + i * 16 + kq * 4;
                int col = bn + wc + j * 16 + m16;
#pragma unroll
                for (int q = 0; q < 4; q++)
                    Cf[(size_t)(row + q) * N + col] = acc[i][j][q];
            }
    } else {
        // C^T through LDS. Last loop iteration ended with __syncthreads(),
        // so As/Bs are free to reuse as the 128x128 bf16 transpose buffer.
        // Layout: Tt[col][row-unit], row-unit = 4 rows (8 B). Add-rotate
        // swizzle u' = (u + 2*col) & 31 spreads banks (<=2-way conflicts)
        // with zero padding, so the buffer is exactly 32 KB.
        unsigned short* Tt = SMEM;
#pragma unroll
        for (int i = 0; i < 4; i++)
#pragma unroll
            for (int j = 0; j < 4; j++) {
                int c = wc + j * 16 + m16;          // local col 0..127 (N-dim)
                int u = (wr >> 2) + i * 4 + kq;     // row unit 0..31 (M-dim/4)
                int us = (u + 2 * c) & 31;
                *reinterpret_cast<uint2*>(&Tt[c * 128 + us * 4]) =
                    pack4(acc[i][j][0], acc[i][j][1], acc[i][j][2], acc[i][j][3]);
            }
        __syncthreads();
        unsigned short* Ct = (unsigned short*)p.C[z];
        int r8 = tid & 15;          // 8-row chunk within tile
        int cb = tid >> 4;          // col offset within pass
#pragma unroll
        for (int pass = 0; pass < 8; pass++) {
            int c  = pass * 16 + cb;
            int u0 = r8 * 2;                       // even -> us,us+1 contiguous
            int us = (u0 + 2 * c) & 31;
            uint4 val = *reinterpret_cast<const uint4*>(&Tt[c * 128 + us * 4]);
            // Key-permuted write: rows key0..key0+7 split into two 4-row
            // (8 B) units at permuted positions p = 8g + 4h + e (h = bit4,
            // g = bits3:2 of the local-32 row index). dst1 = dst0 + 8.
            int key0 = r8 * 8;                     // local row base, step 8
            int loc  = key0 & 31;                  // 0, 8, 16, 24
            int dst0 = (key0 & 96) + (((loc & 15) >> 2) * 8) + ((loc >> 4) * 4);
            unsigned short* out = &Ct[(size_t)(bn + c) * M + bm + dst0];
            *reinterpret_cast<uint2*>(out)     = make_uint2(val.x, val.y);
            *reinterpret_cast<uint2*>(out + 8) = make_uint2(val.z, val.w);
        }
    }
}

// ---------------- flash attention, bf16 MFMA, no-max softmax ----------------
// Q is pre-scaled by 0.125*log2(e) in the projection GEMM epilogue, so
//   p = exp2(k.q_scaled) == exp(q.k/8)  (|q.k/8| <~ 2 -> no-max is safe).
// Row-sum l is folded into the PV stage: extra MFMAs with an all-ones
// A-fragment compute column sums of P^T; in the C/D layout every lane then
// holds l for its own q-column in all regs -> no adds, no shuffles.
// P is packed to bf16 by TRUNCATION; bias cancels in O = (P@V)/(P@1).
// Orientation: St = K @ Q^T (m=key, n=qrow), O^T = V^T @ P^T (m=d, n=qrow).
// Block: 128 q-rows, 4 waves, wave owns 32 q-rows. Key-tile 64. Grid 1024.
//
// v5: key-permuted zero-shuffle PV at K=32.
//     The QK C/D layout gives lane (kq) keys {4kq..4kq+3, 16+4kq..+3} per
//     32-key chunk; the K=32 B-fragment slot map is k = 8kq+e. vtbuf is
//     stored with keys permuted (16h+4g+e -> 8g+4h+e within each 32-group,
//     done in the projection GEMM mode-2 epilogue), so BOTH PV operands see
//     the same key order: P feeds PV directly from registers (4 v_perm
//     packs), V^T is one ds_read_b128 per fragment, all MFMA are K=32
//     (v4's 16x16x16 ran at the same ~19cyc/inst for HALF the FLOPs ->
//     54% MfmaUtil but +5us; this restores the v3 MFMA budget).
//     Keeps v4's: Pt LDS deleted, K/V double-buffer in 32 KB, stage(next)
//     at iter top + single vmcnt(0)+s_barrier at iter end, T5 setprio,
//     XCD-chunked block swizzle (FETCH 141.6 -> 25.6 MB).
__global__ __launch_bounds__(256, 4)
void flash_bf16(const unsigned short* __restrict__ qb,
                const unsigned short* __restrict__ kb,
                const unsigned short* __restrict__ vtb,
                unsigned short* __restrict__ ao) {
    __shared__ __align__(16) unsigned short Ks[2][64 * 64];
    __shared__ __align__(16) unsigned short Vt[2][64 * 64];

    const int tid  = threadIdx.x;
    const int wave = tid >> 6;
    const int lane = tid & 63;
    const int m16  = lane & 15;
    const int kq   = lane >> 4;

    // XCD swizzle: linear dispatch id -> 128-contiguous chunk per XCD.
    const int flat = blockIdx.y * (LSEQ / 128) + blockIdx.x;   // 0..1023
    const int swz  = (flat & 7) * 128 + (flat >> 3);
    const int bh   = swz >> 4;               // 0..63
    const int nn   = bh >> 4;                // batch
    const int h    = bh & 15;                // head
    const int q0   = (swz & 15) * 128;       // query tile base

    // all-ones A-fragment (bf16 1.0 = 0x3F80) for the l-row MFMAs
    const uint4 ones_u = make_uint4(0x3F803F80u, 0x3F803F80u, 0x3F803F80u, 0x3F803F80u);
    const bf16x8 ones8 = __builtin_bit_cast(bf16x8, ones_u);

    const unsigned short* kptr  = kb + (size_t)(nn * LSEQ) * EMBED + h * DQ;
    const unsigned short* vtptr = vtb + (size_t)(h * DQ) * MROWS + nn * LSEQ;

    auto stage = [&](int buf) {
#pragma unroll
        for (int it = 0; it < 2; it++) {
            int c = tid + it * 256;            // chunk 0..511
            int r = c >> 3;                    // row 0..63
            int kc = (c & 7) ^ (r & 7);        // swizzled chunk in row
            async_cp16(kptr + (size_t)r * EMBED + kc * 8,
                       &Ks[buf][(it * 256 + wave * 64) * 8]);
            async_cp16(vtptr + (size_t)r * MROWS + kc * 8,
                       &Vt[buf][(it * 256 + wave * 64) * 8]);
        }
        kptr  += 64 * EMBED;
        vtptr += 64;
    };

    // prologue: stage tile 0; Q fragment loads overlap the staging.
    stage(0);

    // Q fragments: qf[j][s] = Q[q0+wave*32+j*16+m16][s*32 + kq*8 .. +7]
    bf16x8 qf[2][2];
#pragma unroll
    for (int j = 0; j < 2; j++) {
        size_t tok = (size_t)(nn * LSEQ + q0 + wave * 32 + j * 16 + m16);
#pragma unroll
        for (int s = 0; s < 2; s++)
            qf[j][s] = *reinterpret_cast<const bf16x8*>(
                &qb[tok * EMBED + h * DQ + s * 32 + kq * 8]);
    }

    f32x4 o[4][2];   // o[mt][j]: O^T tile (d = mt*16+kq*4+reg, qcol = j*16+m16)
    f32x4 o4[2];     // l accumulator (all regs equal per lane)
#pragma unroll
    for (int j = 0; j < 2; j++) {
        o4[j] = f32x4{0.f, 0.f, 0.f, 0.f};
#pragma unroll
        for (int mt = 0; mt < 4; mt++) o[mt][j] = f32x4{0.f, 0.f, 0.f, 0.f};
    }

    asm volatile("s_waitcnt vmcnt(0)" ::: "memory");   // tile 0 + Q landed
    __builtin_amdgcn_s_barrier();
    asm volatile("" ::: "memory");

    const int NT = LSEQ / 64;    // 32
    for (int kt = 0; kt < NT; kt++) {
        const int cur = kt & 1;
        if (kt + 1 < NT) stage(cur ^ 1);   // prefetch next tile (no wait)

        // St = K @ Q^T : st[i][j], key = i*16+kq*4+reg, qcol = j*16+m16
        f32x4 st[4][2];
#pragma unroll
        for (int i = 0; i < 4; i++)
#pragma unroll
            for (int j = 0; j < 2; j++) st[i][j] = f32x4{0.f, 0.f, 0.f, 0.f};

#pragma unroll
        for (int s = 0; s < 2; s++) {
            bf16x8 ak[4];
#pragma unroll
            for (int i = 0; i < 4; i++) {
                int key = i * 16 + m16;
                ak[i] = *reinterpret_cast<const bf16x8*>(
                    &Ks[cur][key * 64 + (((s * 4 + kq) ^ (m16 & 7)) * 8)]);
            }
            __builtin_amdgcn_s_setprio(1);
#pragma unroll
            for (int i = 0; i < 4; i++)
#pragma unroll
                for (int j = 0; j < 2; j++)
                    st[i][j] = __builtin_amdgcn_mfma_f32_16x16x32_bf16(ak[i], qf[j][s], st[i][j], 0, 0, 0);
            __builtin_amdgcn_s_setprio(0);
        }

        // PV over two 32-key chunks t. V^T fragment: one b128 per (t,mt)
        // (vtbuf keys pre-permuted to the K=32 slot map k=8kq+e).
        // P fragment: pb[j] slots e<4 = st[2t][j][e], e>=4 = st[2t+1][j][e-4].
#pragma unroll
        for (int t = 0; t < 2; t++) {
            bf16x8 av8[4];
#pragma unroll
            for (int mt = 0; mt < 4; mt++) {
                int d = mt * 16 + m16;
                av8[mt] = *reinterpret_cast<const bf16x8*>(
                    &Vt[cur][d * 64 + (((t * 4 + kq) ^ (m16 & 7)) * 8)]);
            }
            // p = exp2(st) for key-blocks 2t, 2t+1 (Q pre-scaled)
#pragma unroll
            for (int ii = 0; ii < 2; ii++)
#pragma unroll
                for (int j = 0; j < 2; j++)
#pragma unroll
                    for (int q = 0; q < 4; q++)
                        st[2 * t + ii][j][q] = __builtin_amdgcn_exp2f(st[2 * t + ii][j][q]);
            bf16x8 pb[2];
#pragma unroll
            for (int j = 0; j < 2; j++) {
                uint4 pu;
                pu.x = pack2t(st[2 * t][j][0],     st[2 * t][j][1]);
                pu.y = pack2t(st[2 * t][j][2],     st[2 * t][j][3]);
                pu.z = pack2t(st[2 * t + 1][j][0], st[2 * t + 1][j][1]);
                pu.w = pack2t(st[2 * t + 1][j][2], st[2 * t + 1][j][3]);
                pb[j] = __builtin_bit_cast(bf16x8, pu);
            }
            __builtin_amdgcn_s_setprio(1);
#pragma unroll
            for (int mt = 0; mt < 4; mt++)
#pragma unroll
                for (int j = 0; j < 2; j++)
                    o[mt][j] = __builtin_amdgcn_mfma_f32_16x16x32_bf16(av8[mt], pb[j], o[mt][j], 0, 0, 0);
#pragma unroll
            for (int j = 0; j < 2; j++)
                o4[j] = __builtin_amdgcn_mfma_f32_16x16x32_bf16(ones8, pb[j], o4[j], 0, 0, 0);
            __builtin_amdgcn_s_setprio(0);
        }

        // Release buf[cur] for next iter's stage; next tile's loads (issued
        // at iter top) drained here, hidden under the compute above.
        if (kt + 1 < NT) {
            asm volatile("s_waitcnt vmcnt(0)" ::: "memory");
            __builtin_amdgcn_s_barrier();
            asm volatile("" ::: "memory");
        }
    }

    // Epilogue: normalize by l (= o4[j][0], identical in all regs), write ao.
#pragma unroll
    for (int j = 0; j < 2; j++) {
        float inv = 1.f / o4[j][0];
        size_t tok = (size_t)(nn * LSEQ + q0 + wave * 32 + j * 16 + m16);
#pragma unroll
        for (int mt = 0; mt < 4; mt++) {
            *reinterpret_cast<uint2*>(&ao[tok * EMBED + h * DQ + mt * 16 + kq * 4]) =
                pack4(o[mt][j][0] * inv, o[mt][j][1] * inv, o[mt][j][2] * inv, o[mt][j][3] * inv);
        }
    }
}

// ---------------- host ----------------
extern "C" void kernel_launch(void* const* d_in, const int* in_sizes, int n_in,
                              void* d_out, int out_size, void* d_ws, size_t ws_size,
                              hipStream_t stream) {
    (void)in_sizes; (void)n_in; (void)out_size; (void)ws_size;
    const float* x     = (const float*)d_in[0];
    const float* W_q   = (const float*)d_in[1];
    const float* W_k   = (const float*)d_in[2];
    const float* W_v   = (const float*)d_in[3];
    const float* W_qp  = (const float*)d_in[4];
    const float* W_kp  = (const float*)d_in[5];
    const float* W_vp  = (const float*)d_in[6];
    const float* W_out = (const float*)d_in[7];

    unsigned short* ws16 = (unsigned short*)d_ws;
    const size_t SZX = (size_t)MROWS * EMBED;   // 8,388,608
    const size_t SZW = (size_t)EMBED * EMBED;   // 1,048,576

    unsigned short* xb    = ws16;
    unsigned short* wqpb  = xb + SZX;
    unsigned short* wkpb  = wqpb + SZW;
    unsigned short* wvpb  = wkpb + SZW;
    unsigned short* woutb = wvpb + SZW;
    unsigned short* wqT   = woutb + SZW;        // transposed bf16 first-layer weights
    unsigned short* wkT   = wqT + SZW;
    unsigned short* wvT   = wkT + SZW;
    unsigned short* weq   = wvT + SZW;          // fused W_eff = W_p @ W
    unsigned short* wek   = weq + SZW;
    unsigned short* wev   = wek + SZW;
    unsigned short* qbuf  = wev + SZW;
    unsigned short* kbuf  = qbuf + SZX;
    unsigned short* vtbuf = kbuf + SZX;
    unsigned short* ao    = vtbuf + SZX;
    // total: 5*SZX + 10*SZW shorts ~= 105 MB

    // 1a) straight converts: x, Wqp, Wkp, Wvp, Wout
    CvtJobs cj;
    cj.src[0] = x;     cj.dst[0] = xb;    cj.n[0] = (int)SZX;
    cj.src[1] = W_qp;  cj.dst[1] = wqpb;  cj.n[1] = (int)SZW;
    cj.src[2] = W_kp;  cj.dst[2] = wkpb;  cj.n[2] = (int)SZW;
    cj.src[3] = W_vp;  cj.dst[3] = wvpb;  cj.n[3] = (int)SZW;
    cj.src[4] = W_out; cj.dst[4] = woutb; cj.n[4] = (int)SZW;
    cvt_bf16<<<dim3(512, 5), 256, 0, stream>>>(cj);

    // 1b) transposed converts: Wq^T, Wk^T, Wv^T
    TransJobs tj;
    tj.src[0] = W_q; tj.src[1] = W_k; tj.src[2] = W_v;
    tj.dst[0] = wqT; tj.dst[1] = wkT; tj.dst[2] = wvT;
    transpose_cvt<<<dim3(16, 16, 3), 256, 0, stream>>>(tj);

    // 2) weight fusion: W_eff = W_p @ W  (NT with B = W^T)
    BGemmArgs fz;
    fz.A[0] = wqpb; fz.A[1] = wkpb; fz.A[2] = wvpb;
    fz.B[0] = wqT;  fz.B[1] = wkT;  fz.B[2] = wvT;
    fz.C[0] = weq;  fz.C[1] = wek;  fz.C[2] = wev;
    fz.mode[0] = 0; fz.mode[1] = 0; fz.mode[2] = 0;
    fz.scl[0] = 1.f; fz.scl[1] = 1.f; fz.scl[2] = 1.f;
    gemm_bf16nt<<<dim3(8, 8, 3), 256, 0, stream>>>(fz, EMBED, EMBED, EMBED);

    // 3) projections: q = (x@Weq^T)*0.125*log2e, k = x@Wek^T, v^T = (x@Wev^T)^T
    //    (mode 2 writes vtbuf with the 32-key-group permutation for flash PV)
    BGemmArgs pj;
    pj.A[0] = xb;   pj.A[1] = xb;   pj.A[2] = xb;
    pj.B[0] = weq;  pj.B[1] = wek;  pj.B[2] = wev;
    pj.C[0] = qbuf; pj.C[1] = kbuf; pj.C[2] = vtbuf;
    pj.mode[0] = 0; pj.mode[1] = 0; pj.mode[2] = 2;
    pj.scl[0] = 0.18033688f; pj.scl[1] = 1.f; pj.scl[2] = 1.f;
    gemm_bf16nt<<<dim3(8, 64, 3), 256, 0, stream>>>(pj, MROWS, EMBED, EMBED);

    // 4) flash attention
    flash_bf16<<<dim3(LSEQ / 128, NB * NH), 256, 0, stream>>>(qbuf, kbuf, vtbuf, ao);

    // 5) out = ao @ W_out^T (fp32 out)
    BGemmArgs og;
    og.A[0] = ao;    og.A[1] = ao;    og.A[2] = ao;
    og.B[0] = woutb; og.B[1] = woutb; og.B[2] = woutb;
    og.C[0] = d_out; og.C[1] = d_out; og.C[2] = d_out;
    og.mode[0] = 1; og.mode[1] = 1; og.mode[2] = 1;
    og.scl[0] = 1.f; og.scl[1] = 1.f; og.scl[2] = 1.f;
    gemm_bf16nt<<<dim3(8, 64, 1), 256, 0, stream>>>(og, MROWS, EMBED, EMBED);
}

// Round 5
// 273.495 us; speedup vs baseline: 1.1181x; 1.0883x over previous
//
#include <hip/hip_runtime.h>
#include <cstddef>
#include <cstdint>

#define EMBED 1024
#define NH    16
#define DQ    64
#define NB    4
#define LSEQ  2048
#define MROWS (NB * LSEQ)   // 8192

typedef __bf16 bf16x8 __attribute__((ext_vector_type(8)));
typedef float  f32x4  __attribute__((ext_vector_type(4)));

// bf16 round-half-up: bias then take high 16. (RNE differs only on exact ties.)
__device__ __forceinline__ unsigned short f2bf(float f) {
    return (unsigned short)((__float_as_uint(f) + 0x8000u) >> 16);
}

// two floats -> packed bf16x2, round-half-up: 2 bias adds + 1 v_perm_b32.
__device__ __forceinline__ unsigned pack2(float a, float b) {
    unsigned ua = __float_as_uint(a) + 0x8000u;
    unsigned ub = __float_as_uint(b) + 0x8000u;
    return __builtin_amdgcn_perm(ub, ua, 0x07060302u);  // [b.hi16 : a.hi16]
}

__device__ __forceinline__ uint2 pack4(float a, float b, float c, float d) {
    return make_uint2(pack2(a, b), pack2(c, d));
}

// truncating pack (1 v_perm, no bias). Used for P where the bias cancels in
// the O = (P@V)/(P@1) ratio since l is computed from the same truncated P.
__device__ __forceinline__ unsigned pack2t(float a, float b) {
    return __builtin_amdgcn_perm(__float_as_uint(b), __float_as_uint(a), 0x07060302u);
}

// async global -> LDS, 16 B per lane. LDS dest = l + lane*16 (wave-uniform base l).
__device__ __forceinline__ void async_cp16(const void* g, void* l) {
    __builtin_amdgcn_global_load_lds((const __attribute__((address_space(1))) unsigned int*)g,
                                     (__attribute__((address_space(3))) unsigned int*)l,
                                     16, 0, 0);
}

// ---------------- fp32 -> bf16 convert (batched) ----------------
struct CvtJobs {
    const float* src[8];
    unsigned short* dst[8];
    int n[8];
};

__global__ __launch_bounds__(256) void cvt_bf16(CvtJobs j) {
    int job = blockIdx.y;
    const float* s = j.src[job];
    unsigned short* d = j.dst[job];
    int n4 = j.n[job] >> 2;
    int stride = gridDim.x * blockDim.x;
    for (int i = blockIdx.x * blockDim.x + threadIdx.x; i < n4; i += stride) {
        float4 f = ((const float4*)s)[i];
        ((uint2*)d)[i] = pack4(f.x, f.y, f.z, f.w);
    }
}

// ---------------- fp32 -> bf16 transposed convert (1024x1024) ----------------
// dst[j][i] = bf16(src[i][j]). 64x64 tiles, grid (16,16,3).
struct TransJobs {
    const float* src[3];
    unsigned short* dst[3];
};

__global__ __launch_bounds__(256) void transpose_cvt(TransJobs tj) {
    __shared__ unsigned short Ts[64][68];
    const float* src = tj.src[blockIdx.z];
    unsigned short* dst = tj.dst[blockIdx.z];
    const int tid = threadIdx.x;
    const int r0 = blockIdx.y * 64;
    const int c0 = blockIdx.x * 64;

    {
        int col4 = tid & 15;
        int rb   = tid >> 4;
#pragma unroll
        for (int it = 0; it < 4; it++) {
            int r = rb + it * 16;
            float4 f = *(const float4*)(src + (size_t)(r0 + r) * 1024 + c0 + col4 * 4);
            *(uint2*)&Ts[r][col4 * 4] = pack4(f.x, f.y, f.z, f.w);
        }
    }
    __syncthreads();

    {
        int oc = tid >> 2;
        int seg = tid & 3;
        __attribute__((aligned(16))) unsigned short tmp[16];
#pragma unroll
        for (int e = 0; e < 16; e++) tmp[e] = Ts[seg * 16 + e][oc];
        unsigned short* out = dst + (size_t)(c0 + oc) * 1024 + r0 + seg * 16;
        *(uint4*)(out)     = *(const uint4*)&tmp[0];
        *(uint4*)(out + 8) = *(const uint4*)&tmp[8];
    }
}

// ---------------- bf16 NT GEMM: C = A(MxK) @ B(NxK)^T ----------------
// 128x128 tile, BK=64 (32 KB LDS, 32 MFMA per barrier pair), 256 threads =
// 4 waves, each wave a 64x64 quadrant of 4x4 mfma_f32_16x16x32_bf16.
// Staging via global_load_lds w=16 with xor chunk swizzle:
//   LDS chunk c (16B) holds global (row r=c>>3, k-chunk (c&7)^(r&7)).
// XCD-chunked block swizzle (per-z nwg is a multiple of 8 in all our
// launches -> bijective): the 8 blocks sharing one A row-panel land on ONE
// XCD's L2 instead of 8, cutting A re-fetch ~8x.
//
// __launch_bounds__(256, 4): gfx950 has a UNIFIED VGPR/AGPR file. At the
// default allocation this kernel was 88 VGPR + 64 AGPR = 152 unified ->
// the (128,256] bin -> 2 waves/SIMD -> 2 blocks/CU -> Occupancy 19%,
// MfmaUtil 27% (no co-resident TLP to hide the 2-phase stage drain).
// Forcing 4 waves/EU makes the allocator fit VGPR <= 64 (acc needs 64
// AGPR), doubling resident blocks. flash_bf16 hits 64 VGPR with a
// comparable inner loop, so the budget is feasible.
//
// mode: 0 = bf16 row-major (acc*scl), 1 = fp32 row-major,
// mode 2 = bf16 C^T (ld=M) with KEY-PERMUTED rows for the flash PV B-layout:
//   within each 32-row group, row 16h+4g+e  is stored at  8g+4h+e.
//   (PV contracts V^T and P^T over the same permuted index; permutation
//   applied identically to both operands leaves the product unchanged.)
//   Transposes through LDS so global writes stay 8B-unit contiguous runs.
struct BGemmArgs {
    const unsigned short* A[3];
    const unsigned short* B[3];
    void* C[3];
    int mode[3];
    float scl[3];
};

__global__ __launch_bounds__(256, 4) void gemm_bf16nt(BGemmArgs p, int M, int N, int K) {
    __shared__ __align__(16) unsigned short SMEM[2 * 128 * 64];
    unsigned short* As = SMEM;
    unsigned short* Bs = SMEM + 128 * 64;

    const int tid  = threadIdx.x;
    const int wave = tid >> 6;
    const int lane = tid & 63;
    const int m16  = lane & 15;
    const int kq   = lane >> 4;

    // XCD swizzle within the z-slice (nwg % 8 == 0 for all our grids).
    const int nwg  = gridDim.x * gridDim.y;
    const int flat = blockIdx.y * gridDim.x + blockIdx.x;
    const int swz  = (flat & 7) * (nwg >> 3) + (flat >> 3);
    const int bm = (swz / gridDim.x) * 128;
    const int bn = (swz % gridDim.x) * 128;
    const int z  = blockIdx.z;
    const unsigned short* A = p.A[z];
    const unsigned short* B = p.B[z];

    f32x4 acc[4][4];
#pragma unroll
    for (int i = 0; i < 4; i++)
#pragma unroll
        for (int j = 0; j < 4; j++) acc[i][j] = f32x4{0.f, 0.f, 0.f, 0.f};

    const int wr = (wave >> 1) * 64;
    const int wc = (wave & 1) * 64;

    for (int k0 = 0; k0 < K; k0 += 64) {
#pragma unroll
        for (int it = 0; it < 4; it++) {
            int c = tid + it * 256;         // chunk 0..1023
            int r = c >> 3;                 // tile row 0..127
            int kc = (c & 7) ^ (r & 7);     // swizzled k-chunk in row
            async_cp16(A + (size_t)(bm + r) * K + k0 + kc * 8,
                       &As[(it * 256 + wave * 64) * 8]);
            async_cp16(B + (size_t)(bn + r) * K + k0 + kc * 8,
                       &Bs[(it * 256 + wave * 64) * 8]);
        }
        __syncthreads();

#pragma unroll
        for (int s = 0; s < 2; s++) {
            bf16x8 af[4], bfr[4];
#pragma unroll
            for (int i = 0; i < 4; i++) {
                int ra = wr + i * 16 + m16;
                af[i] = *reinterpret_cast<const bf16x8*>(
                    &As[ra * 64 + (((s * 4 + kq) ^ (ra & 7)) * 8)]);
                int rb = wc + i * 16 + m16;
                bfr[i] = *reinterpret_cast<const bf16x8*>(
                    &Bs[rb * 64 + (((s * 4 + kq) ^ (rb & 7)) * 8)]);
            }
#pragma unroll
            for (int i = 0; i < 4; i++)
#pragma unroll
                for (int j = 0; j < 4; j++)
                    acc[i][j] = __builtin_amdgcn_mfma_f32_16x16x32_bf16(af[i], bfr[j], acc[i][j], 0, 0, 0);
        }
        __syncthreads();
    }

    const int mode = p.mode[z];
    const float scl = p.scl[z];
    if (mode == 0) {
        unsigned short* Cb = (unsigned short*)p.C[z];
#pragma unroll
        for (int i = 0; i < 4; i++)
#pragma unroll
            for (int j = 0; j < 4; j++) {
                int row = bm + wr + i * 16 + kq * 4;
                int col = bn + wc + j * 16 + m16;
#pragma unroll
                for (int q = 0; q < 4; q++)
                    Cb[(size_t)(row + q) * N + col] = f2bf(acc[i][j][q] * scl);
            }
    } else if (mode == 1) {
        float* Cf = (float*)p.C[z];
#pragma unroll
        for (int i = 0; i < 4; i++)
#pragma unroll
            for (int j = 0; j < 4; j++) {
                int row = bm + wr + i * 16 + kq * 4;
                int col = bn + wc + j * 16 + m16;
#pragma unroll
                for (int q = 0; q < 4; q++)
                    Cf[(size_t)(row + q) * N + col] = acc[i][j][q];
            }
    } else {
        // C^T through LDS. Last loop iteration ended with __syncthreads(),
        // so As/Bs are free to reuse as the 128x128 bf16 transpose buffer.
        // Layout: Tt[col][row-unit], row-unit = 4 rows (8 B). Add-rotate
        // swizzle u' = (u + 2*col) & 31 spreads banks (<=2-way conflicts)
        // with zero padding, so the buffer is exactly 32 KB.
        unsigned short* Tt = SMEM;
#pragma unroll
        for (int i = 0; i < 4; i++)
#pragma unroll
            for (int j = 0; j < 4; j++) {
                int c = wc + j * 16 + m16;          // local col 0..127 (N-dim)
                int u = (wr >> 2) + i * 4 + kq;     // row unit 0..31 (M-dim/4)
                int us = (u + 2 * c) & 31;
                *reinterpret_cast<uint2*>(&Tt[c * 128 + us * 4]) =
                    pack4(acc[i][j][0], acc[i][j][1], acc[i][j][2], acc[i][j][3]);
            }
        __syncthreads();
        unsigned short* Ct = (unsigned short*)p.C[z];
        int r8 = tid & 15;          // 8-row chunk within tile
        int cb = tid >> 4;          // col offset within pass
#pragma unroll
        for (int pass = 0; pass < 8; pass++) {
            int c  = pass * 16 + cb;
            int u0 = r8 * 2;                       // even -> us,us+1 contiguous
            int us = (u0 + 2 * c) & 31;
            uint4 val = *reinterpret_cast<const uint4*>(&Tt[c * 128 + us * 4]);
            // Key-permuted write: rows key0..key0+7 split into two 4-row
            // (8 B) units at permuted positions p = 8g + 4h + e (h = bit4,
            // g = bits3:2 of the local-32 row index). dst1 = dst0 + 8.
            int key0 = r8 * 8;                     // local row base, step 8
            int loc  = key0 & 31;                  // 0, 8, 16, 24
            int dst0 = (key0 & 96) + (((loc & 15) >> 2) * 8) + ((loc >> 4) * 4);
            unsigned short* out = &Ct[(size_t)(bn + c) * M + bm + dst0];
            *reinterpret_cast<uint2*>(out)     = make_uint2(val.x, val.y);
            *reinterpret_cast<uint2*>(out + 8) = make_uint2(val.z, val.w);
        }
    }
}

// ---------------- flash attention, bf16 MFMA, no-max softmax ----------------
// Q is pre-scaled by 0.125*log2(e) in the projection GEMM epilogue, so
//   p = exp2(k.q_scaled) == exp(q.k/8)  (|q.k/8| <~ 2 -> no-max is safe).
// Row-sum l is folded into the PV stage: extra MFMAs with an all-ones
// A-fragment compute column sums of P^T; in the C/D layout every lane then
// holds l for its own q-column in all regs -> no adds, no shuffles.
// P is packed to bf16 by TRUNCATION; bias cancels in O = (P@V)/(P@1).
// Orientation: St = K @ Q^T (m=key, n=qrow), O^T = V^T @ P^T (m=d, n=qrow).
// Block: 128 q-rows, 4 waves, wave owns 32 q-rows. Key-tile 64. Grid 1024.
//
// v5: key-permuted zero-shuffle PV at K=32.
//     The QK C/D layout gives lane (kq) keys {4kq..4kq+3, 16+4kq..+3} per
//     32-key chunk; the K=32 B-fragment slot map is k = 8kq+e. vtbuf is
//     stored with keys permuted (16h+4g+e -> 8g+4h+e within each 32-group,
//     done in the projection GEMM mode-2 epilogue), so BOTH PV operands see
//     the same key order: P feeds PV directly from registers (4 v_perm
//     packs), V^T is one ds_read_b128 per fragment, all MFMA are K=32.
//     Keeps: Pt LDS deleted, K/V double-buffer in 32 KB, stage(next)
//     at iter top + single vmcnt(0)+s_barrier at iter end, T5 setprio,
//     XCD-chunked block swizzle (FETCH 141.6 -> 25.6 MB).
__global__ __launch_bounds__(256, 4)
void flash_bf16(const unsigned short* __restrict__ qb,
                const unsigned short* __restrict__ kb,
                const unsigned short* __restrict__ vtb,
                unsigned short* __restrict__ ao) {
    __shared__ __align__(16) unsigned short Ks[2][64 * 64];
    __shared__ __align__(16) unsigned short Vt[2][64 * 64];

    const int tid  = threadIdx.x;
    const int wave = tid >> 6;
    const int lane = tid & 63;
    const int m16  = lane & 15;
    const int kq   = lane >> 4;

    // XCD swizzle: linear dispatch id -> 128-contiguous chunk per XCD.
    const int flat = blockIdx.y * (LSEQ / 128) + blockIdx.x;   // 0..1023
    const int swz  = (flat & 7) * 128 + (flat >> 3);
    const int bh   = swz >> 4;               // 0..63
    const int nn   = bh >> 4;                // batch
    const int h    = bh & 15;                // head
    const int q0   = (swz & 15) * 128;       // query tile base

    // all-ones A-fragment (bf16 1.0 = 0x3F80) for the l-row MFMAs
    const uint4 ones_u = make_uint4(0x3F803F80u, 0x3F803F80u, 0x3F803F80u, 0x3F803F80u);
    const bf16x8 ones8 = __builtin_bit_cast(bf16x8, ones_u);

    const unsigned short* kptr  = kb + (size_t)(nn * LSEQ) * EMBED + h * DQ;
    const unsigned short* vtptr = vtb + (size_t)(h * DQ) * MROWS + nn * LSEQ;

    auto stage = [&](int buf) {
#pragma unroll
        for (int it = 0; it < 2; it++) {
            int c = tid + it * 256;            // chunk 0..511
            int r = c >> 3;                    // row 0..63
            int kc = (c & 7) ^ (r & 7);        // swizzled chunk in row
            async_cp16(kptr + (size_t)r * EMBED + kc * 8,
                       &Ks[buf][(it * 256 + wave * 64) * 8]);
            async_cp16(vtptr + (size_t)r * MROWS + kc * 8,
                       &Vt[buf][(it * 256 + wave * 64) * 8]);
        }
        kptr  += 64 * EMBED;
        vtptr += 64;
    };

    // prologue: stage tile 0; Q fragment loads overlap the staging.
    stage(0);

    // Q fragments: qf[j][s] = Q[q0+wave*32+j*16+m16][s*32 + kq*8 .. +7]
    bf16x8 qf[2][2];
#pragma unroll
    for (int j = 0; j < 2; j++) {
        size_t tok = (size_t)(nn * LSEQ + q0 + wave * 32 + j * 16 + m16);
#pragma unroll
        for (int s = 0; s < 2; s++)
            qf[j][s] = *reinterpret_cast<const bf16x8*>(
                &qb[tok * EMBED + h * DQ + s * 32 + kq * 8]);
    }

    f32x4 o[4][2];   // o[mt][j]: O^T tile (d = mt*16+kq*4+reg, qcol = j*16+m16)
    f32x4 o4[2];     // l accumulator (all regs equal per lane)
#pragma unroll
    for (int j = 0; j < 2; j++) {
        o4[j] = f32x4{0.f, 0.f, 0.f, 0.f};
#pragma unroll
        for (int mt = 0; mt < 4; mt++) o[mt][j] = f32x4{0.f, 0.f, 0.f, 0.f};
    }

    asm volatile("s_waitcnt vmcnt(0)" ::: "memory");   // tile 0 + Q landed
    __builtin_amdgcn_s_barrier();
    asm volatile("" ::: "memory");

    const int NT = LSEQ / 64;    // 32
    for (int kt = 0; kt < NT; kt++) {
        const int cur = kt & 1;
        if (kt + 1 < NT) stage(cur ^ 1);   // prefetch next tile (no wait)

        // St = K @ Q^T : st[i][j], key = i*16+kq*4+reg, qcol = j*16+m16
        f32x4 st[4][2];
#pragma unroll
        for (int i = 0; i < 4; i++)
#pragma unroll
            for (int j = 0; j < 2; j++) st[i][j] = f32x4{0.f, 0.f, 0.f, 0.f};

#pragma unroll
        for (int s = 0; s < 2; s++) {
            bf16x8 ak[4];
#pragma unroll
            for (int i = 0; i < 4; i++) {
                int key = i * 16 + m16;
                ak[i] = *reinterpret_cast<const bf16x8*>(
                    &Ks[cur][key * 64 + (((s * 4 + kq) ^ (m16 & 7)) * 8)]);
            }
            __builtin_amdgcn_s_setprio(1);
#pragma unroll
            for (int i = 0; i < 4; i++)
#pragma unroll
                for (int j = 0; j < 2; j++)
                    st[i][j] = __builtin_amdgcn_mfma_f32_16x16x32_bf16(ak[i], qf[j][s], st[i][j], 0, 0, 0);
            __builtin_amdgcn_s_setprio(0);
        }

        // PV over two 32-key chunks t. V^T fragment: one b128 per (t,mt)
        // (vtbuf keys pre-permuted to the K=32 slot map k=8kq+e).
        // P fragment: pb[j] slots e<4 = st[2t][j][e], e>=4 = st[2t+1][j][e-4].
#pragma unroll
        for (int t = 0; t < 2; t++) {
            bf16x8 av8[4];
#pragma unroll
            for (int mt = 0; mt < 4; mt++) {
                int d = mt * 16 + m16;
                av8[mt] = *reinterpret_cast<const bf16x8*>(
                    &Vt[cur][d * 64 + (((t * 4 + kq) ^ (m16 & 7)) * 8)]);
            }
            // p = exp2(st) for key-blocks 2t, 2t+1 (Q pre-scaled)
#pragma unroll
            for (int ii = 0; ii < 2; ii++)
#pragma unroll
                for (int j = 0; j < 2; j++)
#pragma unroll
                    for (int q = 0; q < 4; q++)
                        st[2 * t + ii][j][q] = __builtin_amdgcn_exp2f(st[2 * t + ii][j][q]);
            bf16x8 pb[2];
#pragma unroll
            for (int j = 0; j < 2; j++) {
                uint4 pu;
                pu.x = pack2t(st[2 * t][j][0],     st[2 * t][j][1]);
                pu.y = pack2t(st[2 * t][j][2],     st[2 * t][j][3]);
                pu.z = pack2t(st[2 * t + 1][j][0], st[2 * t + 1][j][1]);
                pu.w = pack2t(st[2 * t + 1][j][2], st[2 * t + 1][j][3]);
                pb[j] = __builtin_bit_cast(bf16x8, pu);
            }
            __builtin_amdgcn_s_setprio(1);
#pragma unroll
            for (int mt = 0; mt < 4; mt++)
#pragma unroll
                for (int j = 0; j < 2; j++)
                    o[mt][j] = __builtin_amdgcn_mfma_f32_16x16x32_bf16(av8[mt], pb[j], o[mt][j], 0, 0, 0);
#pragma unroll
            for (int j = 0; j < 2; j++)
                o4[j] = __builtin_amdgcn_mfma_f32_16x16x32_bf16(ones8, pb[j], o4[j], 0, 0, 0);
            __builtin_amdgcn_s_setprio(0);
        }

        // Release buf[cur] for next iter's stage; next tile's loads (issued
        // at iter top) drained here, hidden under the compute above.
        if (kt + 1 < NT) {
            asm volatile("s_waitcnt vmcnt(0)" ::: "memory");
            __builtin_amdgcn_s_barrier();
            asm volatile("" ::: "memory");
        }
    }

    // Epilogue: normalize by l (= o4[j][0], identical in all regs), write ao.
#pragma unroll
    for (int j = 0; j < 2; j++) {
        float inv = 1.f / o4[j][0];
        size_t tok = (size_t)(nn * LSEQ + q0 + wave * 32 + j * 16 + m16);
#pragma unroll
        for (int mt = 0; mt < 4; mt++) {
            *reinterpret_cast<uint2*>(&ao[tok * EMBED + h * DQ + mt * 16 + kq * 4]) =
                pack4(o[mt][j][0] * inv, o[mt][j][1] * inv, o[mt][j][2] * inv, o[mt][j][3] * inv);
        }
    }
}

// ---------------- host ----------------
extern "C" void kernel_launch(void* const* d_in, const int* in_sizes, int n_in,
                              void* d_out, int out_size, void* d_ws, size_t ws_size,
                              hipStream_t stream) {
    (void)in_sizes; (void)n_in; (void)out_size; (void)ws_size;
    const float* x     = (const float*)d_in[0];
    const float* W_q   = (const float*)d_in[1];
    const float* W_k   = (const float*)d_in[2];
    const float* W_v   = (const float*)d_in[3];
    const float* W_qp  = (const float*)d_in[4];
    const float* W_kp  = (const float*)d_in[5];
    const float* W_vp  = (const float*)d_in[6];
    const float* W_out = (const float*)d_in[7];

    unsigned short* ws16 = (unsigned short*)d_ws;
    const size_t SZX = (size_t)MROWS * EMBED;   // 8,388,608
    const size_t SZW = (size_t)EMBED * EMBED;   // 1,048,576

    unsigned short* xb    = ws16;
    unsigned short* wqpb  = xb + SZX;
    unsigned short* wkpb  = wqpb + SZW;
    unsigned short* wvpb  = wkpb + SZW;
    unsigned short* woutb = wvpb + SZW;
    unsigned short* wqT   = woutb + SZW;        // transposed bf16 first-layer weights
    unsigned short* wkT   = wqT + SZW;
    unsigned short* wvT   = wkT + SZW;
    unsigned short* weq   = wvT + SZW;          // fused W_eff = W_p @ W
    unsigned short* wek   = weq + SZW;
    unsigned short* wev   = wek + SZW;
    unsigned short* qbuf  = wev + SZW;
    unsigned short* kbuf  = qbuf + SZX;
    unsigned short* vtbuf = kbuf + SZX;
    unsigned short* ao    = vtbuf + SZX;
    // total: 5*SZX + 10*SZW shorts ~= 105 MB

    // 1a) straight converts: x, Wqp, Wkp, Wvp, Wout
    CvtJobs cj;
    cj.src[0] = x;     cj.dst[0] = xb;    cj.n[0] = (int)SZX;
    cj.src[1] = W_qp;  cj.dst[1] = wqpb;  cj.n[1] = (int)SZW;
    cj.src[2] = W_kp;  cj.dst[2] = wkpb;  cj.n[2] = (int)SZW;
    cj.src[3] = W_vp;  cj.dst[3] = wvpb;  cj.n[3] = (int)SZW;
    cj.src[4] = W_out; cj.dst[4] = woutb; cj.n[4] = (int)SZW;
    cvt_bf16<<<dim3(512, 5), 256, 0, stream>>>(cj);

    // 1b) transposed converts: Wq^T, Wk^T, Wv^T
    TransJobs tj;
    tj.src[0] = W_q; tj.src[1] = W_k; tj.src[2] = W_v;
    tj.dst[0] = wqT; tj.dst[1] = wkT; tj.dst[2] = wvT;
    transpose_cvt<<<dim3(16, 16, 3), 256, 0, stream>>>(tj);

    // 2) weight fusion: W_eff = W_p @ W  (NT with B = W^T)
    BGemmArgs fz;
    fz.A[0] = wqpb; fz.A[1] = wkpb; fz.A[2] = wvpb;
    fz.B[0] = wqT;  fz.B[1] = wkT;  fz.B[2] = wvT;
    fz.C[0] = weq;  fz.C[1] = wek;  fz.C[2] = wev;
    fz.mode[0] = 0; fz.mode[1] = 0; fz.mode[2] = 0;
    fz.scl[0] = 1.f; fz.scl[1] = 1.f; fz.scl[2] = 1.f;
    gemm_bf16nt<<<dim3(8, 8, 3), 256, 0, stream>>>(fz, EMBED, EMBED, EMBED);

    // 3) projections: q = (x@Weq^T)*0.125*log2e, k = x@Wek^T, v^T = (x@Wev^T)^T
    //    (mode 2 writes vtbuf with the 32-key-group permutation for flash PV)
    BGemmArgs pj;
    pj.A[0] = xb;   pj.A[1] = xb;   pj.A[2] = xb;
    pj.B[0] = weq;  pj.B[1] = wek;  pj.B[2] = wev;
    pj.C[0] = qbuf; pj.C[1] = kbuf; pj.C[2] = vtbuf;
    pj.mode[0] = 0; pj.mode[1] = 0; pj.mode[2] = 2;
    pj.scl[0] = 0.18033688f; pj.scl[1] = 1.f; pj.scl[2] = 1.f;
    gemm_bf16nt<<<dim3(8, 64, 3), 256, 0, stream>>>(pj, MROWS, EMBED, EMBED);

    // 4) flash attention
    flash_bf16<<<dim3(LSEQ / 128, NB * NH), 256, 0, stream>>>(qbuf, kbuf, vtbuf, ao);

    // 5) out = ao @ W_out^T (fp32 out)
    BGemmArgs og;
    og.A[0] = ao;    og.A[1] = ao;    og.A[2] = ao;
    og.B[0] = woutb; og.B[1] = woutb; og.B[2] = woutb;
    og.C[0] = d_out; og.C[1] = d_out; og.C[2] = d_out;
    og.mode[0] = 1; og.mode[1] = 1; og.mode[2] = 1;
    og.scl[0] = 1.f; og.scl[1] = 1.f; og.scl[2] = 1.f;
    gemm_bf16nt<<<dim3(8, 64, 1), 256, 0, stream>>>(og, MROWS, EMBED, EMBED);
}